// Round 1
// baseline (46.863 us; speedup 1.0000x reference)
//
#include <hip/hip_runtime.h>

// Problem constants (from reference)
#define B_      4
#define L_      512
#define S_      100
#define NG_     19
#define GS_     5
#define VOCAB_  6
#define HID_    512
#define HPOOL_  4
#define D_      64
#define ALL_    256      // HPOOL * D
#define FIREH_  32
#define MAXDIST_ 20.0f
// TIME_SCALE = 1.0 (folded)

// ws layout (floats): [0..99] bias, [128..128+24*512) W2 table (v*4+h major, d minor)
// total ws usage: 49,664 bytes (assumed <= ws_size)

// ---------------------------------------------------------------------------
// K1: precompute FIRE bias (100 values) and W2[v*4+h][d] = value_emb slice @ ffn_w
// grid = 25 blocks x 512 threads. blocks 0..23 -> one (v,h) pair each; block 24 -> bias.
// ---------------------------------------------------------------------------
__global__ void prep_kernel(
    const float* __restrict__ dist,      // (100,)
    const float* __restrict__ value_emb, // (6,256)
    const float* __restrict__ ffn_w,     // (256,512)
    const float* __restrict__ fire_c,    // (1,)
    const float* __restrict__ fire_w1,   // (32,)
    const float* __restrict__ fire_w2,   // (32,)
    float* __restrict__ bias_out,        // ws + 0
    float* __restrict__ W2_out)          // ws + 128
{
  const int q = blockIdx.x;
  const int t = threadIdx.x;
  if (q < VOCAB_ * HPOOL_) {
    const int v = q >> 2;
    const int h = q & 3;
    float acc = 0.f;
#pragma unroll
    for (int k = 0; k < D_; ++k) {
      acc = fmaf(value_emb[v * ALL_ + h * D_ + k],
                 ffn_w[(h * D_ + k) * HID_ + t], acc);
    }
    W2_out[q * HID_ + t] = acc;
  } else {
    if (t < S_) {
      const float c = fmaxf(fire_c[0], 0.f);
      const float denom = logf(fmaf(c, MAXDIST_, 1.f));
      const float rel = logf(fmaf(c, dist[t], 1.f)) / denom;
      float acc = 0.f;
#pragma unroll
      for (int i = 0; i < FIREH_; ++i) {
        const float x = rel * fire_w1[i];
        const float s = x / (1.f + expf(-x));   // silu
        acc = fmaf(s, fire_w2[i], acc);
      }
      bias_out[t] = acc;
    }
  }
}

// ---------------------------------------------------------------------------
// K2: main. One block per (b,l). 128 threads; thread t owns output cols 4t..4t+3.
// Phase A: 76 threads (n,h) compute softmax over g=0..4 and scatter into dense
//          cw[19][24] in LDS (cw[n][v*4+h] = sum_g p*[id==v]).
// Phase B: out[n][d] = ffn_b[d] + sum_q cw[n][q]*W2[q][d]; singles = embed_tab gather.
// ---------------------------------------------------------------------------
__global__ __launch_bounds__(128) void main_kernel(
    const int*   __restrict__ ids,       // (B*L, 100)
    const float* __restrict__ attn_w,    // (6,4)
    const float* __restrict__ embed_tab, // (6,512)
    const float* __restrict__ ffn_b,     // (512,)
    const float* __restrict__ bias,      // (100,) from ws
    const float* __restrict__ W2,        // (24,512) from ws
    float* __restrict__ out)             // (B*L, 24, 512)
{
  const int bl = blockIdx.x;
  const int t  = threadIdx.x;

  __shared__ int s_ids[S_];
  __shared__ __align__(16) float s_cw[NG_][24];

  if (t < S_) s_ids[t] = ids[bl * S_ + t];
#pragma unroll
  for (int i = t; i < NG_ * 24; i += 128) ((float*)s_cw)[i] = 0.f;
  __syncthreads();

  if (t < NG_ * HPOOL_) {              // 76 threads
    const int n = t >> 2;
    const int h = t & 3;
    int   idg[GS_];
    float p[GS_];
    float m = -1e30f;
#pragma unroll
    for (int g = 0; g < GS_; ++g) {
      idg[g] = s_ids[n * GS_ + g];
      p[g] = attn_w[idg[g] * HPOOL_ + h] + bias[n * GS_ + g];
      m = fmaxf(m, p[g]);
    }
    float s = 0.f;
#pragma unroll
    for (int g = 0; g < GS_; ++g) { p[g] = expf(p[g] - m); s += p[g]; }
    const float inv = 1.f / s;
#pragma unroll
    for (int g = 0; g < GS_; ++g) {
      // scatter-add; thread (n,h) exclusively owns s_cw[n][*4+h] -> no races
      s_cw[n][idg[g] * HPOOL_ + h] += p[g] * inv;
    }
  }
  __syncthreads();

  // Phase B
  float4 w2r[24];
#pragma unroll
  for (int q = 0; q < 24; ++q)
    w2r[q] = *(const float4*)&W2[q * HID_ + 4 * t];
  const float4 bb = *(const float4*)&ffn_b[4 * t];

  float* op = out + (size_t)bl * 24 * HID_ + 4 * t;

  for (int n = 0; n < NG_; ++n) {
    float4 acc = bb;
    const float4* cw4 = (const float4*)s_cw[n];
#pragma unroll
    for (int q4 = 0; q4 < 6; ++q4) {
      const float4 c = cw4[q4];                      // wave-uniform broadcast read
      acc.x = fmaf(c.x, w2r[q4 * 4 + 0].x, acc.x);
      acc.y = fmaf(c.x, w2r[q4 * 4 + 0].y, acc.y);
      acc.z = fmaf(c.x, w2r[q4 * 4 + 0].z, acc.z);
      acc.w = fmaf(c.x, w2r[q4 * 4 + 0].w, acc.w);
      acc.x = fmaf(c.y, w2r[q4 * 4 + 1].x, acc.x);
      acc.y = fmaf(c.y, w2r[q4 * 4 + 1].y, acc.y);
      acc.z = fmaf(c.y, w2r[q4 * 4 + 1].z, acc.z);
      acc.w = fmaf(c.y, w2r[q4 * 4 + 1].w, acc.w);
      acc.x = fmaf(c.z, w2r[q4 * 4 + 2].x, acc.x);
      acc.y = fmaf(c.z, w2r[q4 * 4 + 2].y, acc.y);
      acc.z = fmaf(c.z, w2r[q4 * 4 + 2].z, acc.z);
      acc.w = fmaf(c.z, w2r[q4 * 4 + 2].w, acc.w);
      acc.x = fmaf(c.w, w2r[q4 * 4 + 3].x, acc.x);
      acc.y = fmaf(c.w, w2r[q4 * 4 + 3].y, acc.y);
      acc.z = fmaf(c.w, w2r[q4 * 4 + 3].z, acc.z);
      acc.w = fmaf(c.w, w2r[q4 * 4 + 3].w, acc.w);
    }
    *(float4*)(op + n * HID_) = acc;
  }

  // singles: rows 19..23 = embed_tab[ids[95+j]]
#pragma unroll
  for (int j = 0; j < 5; ++j) {
    const int id = s_ids[NG_ * GS_ + j];
    *(float4*)(op + (NG_ + j) * HID_) =
        *(const float4*)&embed_tab[id * HID_ + 4 * t];
  }
}

// ---------------------------------------------------------------------------
extern "C" void kernel_launch(void* const* d_in, const int* in_sizes, int n_in,
                              void* d_out, int out_size, void* d_ws, size_t ws_size,
                              hipStream_t stream) {
  const int*   src_ids = (const int*)  d_in[0];
  const float* dist    = (const float*)d_in[1];
  const float* attn_w  = (const float*)d_in[2];
  const float* valemb  = (const float*)d_in[3];
  const float* ffn_w   = (const float*)d_in[4];
  const float* ffn_b   = (const float*)d_in[5];
  const float* emb_tab = (const float*)d_in[6];
  const float* fire_c  = (const float*)d_in[7];
  const float* fire_w1 = (const float*)d_in[8];
  const float* fire_w2 = (const float*)d_in[9];

  float* out  = (float*)d_out;
  float* ws   = (float*)d_ws;
  float* bias = ws;         // 100 floats
  float* W2   = ws + 128;   // 24*512 floats (16B-aligned)

  hipLaunchKernelGGL(prep_kernel, dim3(25), dim3(512), 0, stream,
                     dist, valemb, ffn_w, fire_c, fire_w1, fire_w2, bias, W2);
  hipLaunchKernelGGL(main_kernel, dim3(B_ * L_), dim3(128), 0, stream,
                     src_ids, attn_w, emb_tab, ffn_b, bias, W2, out);
}

// Round 2
// 31.474 us; speedup vs baseline: 1.4889x; 1.4889x over previous
//
#include <hip/hip_runtime.h>

// Problem constants (from reference)
#define B_      4
#define L_      512
#define S_      100
#define NG_     19
#define GS_     5
#define VOCAB_  6
#define HID_    512
#define HPOOL_  4
#define D_      64
#define ALL_    256      // HPOOL * D
#define FIREH_  32
#define MAXDIST_ 20.0f
// TIME_SCALE = 1.0 (folded)

// ws layout (floats): [0..99] bias, [128..128+24*512) W2 table (q = v*4+h major, d minor)
// total ws usage: 49,664 bytes

// ---------------------------------------------------------------------------
// K1: precompute FIRE bias (100 values) and W2[v*4+h][d] = value_emb slice @ ffn_w
// grid = 97 blocks x 128 threads. blocks 0..95 -> (q=blk>>2, colseg=blk&3);
// block 96 -> bias.
// ---------------------------------------------------------------------------
__global__ __launch_bounds__(128) void prep_kernel(
    const float* __restrict__ dist,      // (100,)
    const float* __restrict__ value_emb, // (6,256)
    const float* __restrict__ ffn_w,     // (256,512)
    const float* __restrict__ fire_c,    // (1,)
    const float* __restrict__ fire_w1,   // (32,)
    const float* __restrict__ fire_w2,   // (32,)
    float* __restrict__ bias_out,        // ws + 0
    float* __restrict__ W2_out)          // ws + 128
{
  const int b = blockIdx.x;
  const int t = threadIdx.x;
  if (b < VOCAB_ * HPOOL_ * 4) {
    const int q   = b >> 2;            // 0..23
    const int col = (b & 3) * 128 + t; // 0..511
    const int v = q >> 2;
    const int h = q & 3;
    float acc = 0.f;
#pragma unroll
    for (int k = 0; k < D_; ++k) {
      acc = fmaf(value_emb[v * ALL_ + h * D_ + k],
                 ffn_w[(h * D_ + k) * HID_ + col], acc);
    }
    W2_out[q * HID_ + col] = acc;
  } else {
    if (t < S_) {
      const float c = fmaxf(fire_c[0], 0.f);
      const float denom = logf(fmaf(c, MAXDIST_, 1.f));
      const float rel = logf(fmaf(c, dist[t], 1.f)) / denom;
      float acc = 0.f;
#pragma unroll
      for (int i = 0; i < FIREH_; ++i) {
        const float x = rel * fire_w1[i];
        const float s = x / (1.f + expf(-x));   // silu
        acc = fmaf(s, fire_w2[i], acc);
      }
      bias_out[t] = acc;
    }
  }
}

// ---------------------------------------------------------------------------
// K2: main. One block per (b,l). 256 threads; thread t owns output cols 2t..2t+1.
// Phase A: 76 threads (n,h) compute softmax over g=0..4 and scatter into dense
//          cw[19][24] in LDS (cw[n][v*4+h] = sum_g p*[id==v]).
// Phase B: out[n][d] = ffn_b[d] + sum_q cw[n][q]*W2[q][d]; singles gather.
// w2r is float2[24] = 48 VGPRs -> high occupancy (vs float4[24]=96 before).
// ---------------------------------------------------------------------------
__global__ __launch_bounds__(256) void main_kernel(
    const int*   __restrict__ ids,       // (B*L, 100)
    const float* __restrict__ attn_w,    // (6,4)
    const float* __restrict__ embed_tab, // (6,512)
    const float* __restrict__ ffn_b,     // (512,)
    const float* __restrict__ bias,      // (100,) from ws
    const float* __restrict__ W2,        // (24,512) from ws
    float* __restrict__ out)             // (B*L, 24, 512)
{
  const int bl = blockIdx.x;
  const int t  = threadIdx.x;

  __shared__ int s_ids[S_];
  __shared__ float s_bias[S_];
  __shared__ float s_aw[VOCAB_ * HPOOL_];
  __shared__ __align__(16) float s_cw[NG_][24];

  if (t < S_) s_ids[t] = ids[bl * S_ + t];
  else if (t >= 100 && t < 200) s_bias[t - 100] = bias[t - 100];
  else if (t >= 224 && t < 248) s_aw[t - 224] = attn_w[t - 224];
#pragma unroll
  for (int i = t; i < NG_ * 24; i += 256) ((float*)s_cw)[i] = 0.f;
  __syncthreads();

  if (t < NG_ * HPOOL_) {              // 76 threads
    const int n = t >> 2;
    const int h = t & 3;
    int   idg[GS_];
    float p[GS_];
    float m = -1e30f;
#pragma unroll
    for (int g = 0; g < GS_; ++g) {
      idg[g] = s_ids[n * GS_ + g];
      p[g] = s_aw[idg[g] * HPOOL_ + h] + s_bias[n * GS_ + g];
      m = fmaxf(m, p[g]);
    }
    float s = 0.f;
#pragma unroll
    for (int g = 0; g < GS_; ++g) { p[g] = expf(p[g] - m); s += p[g]; }
    const float inv = 1.f / s;
#pragma unroll
    for (int g = 0; g < GS_; ++g) {
      // scatter-add; thread (n,h) exclusively owns s_cw[n][*4+h] -> no races
      s_cw[n][idg[g] * HPOOL_ + h] += p[g] * inv;
    }
  }
  __syncthreads();

  // Phase B: thread t -> output cols 2t, 2t+1
  float2 w2r[24];
#pragma unroll
  for (int q = 0; q < 24; ++q)
    w2r[q] = *(const float2*)&W2[q * HID_ + 2 * t];
  const float2 bb = *(const float2*)&ffn_b[2 * t];

  float* op = out + (size_t)bl * 24 * HID_ + 2 * t;

  for (int n = 0; n < NG_; ++n) {
    float2 acc = bb;
    const float4* cw4 = (const float4*)s_cw[n];
#pragma unroll
    for (int q4 = 0; q4 < 6; ++q4) {
      const float4 c = cw4[q4];                      // wave-uniform broadcast read
      acc.x = fmaf(c.x, w2r[q4 * 4 + 0].x, acc.x);
      acc.y = fmaf(c.x, w2r[q4 * 4 + 0].y, acc.y);
      acc.x = fmaf(c.y, w2r[q4 * 4 + 1].x, acc.x);
      acc.y = fmaf(c.y, w2r[q4 * 4 + 1].y, acc.y);
      acc.x = fmaf(c.z, w2r[q4 * 4 + 2].x, acc.x);
      acc.y = fmaf(c.z, w2r[q4 * 4 + 2].y, acc.y);
      acc.x = fmaf(c.w, w2r[q4 * 4 + 3].x, acc.x);
      acc.y = fmaf(c.w, w2r[q4 * 4 + 3].y, acc.y);
    }
    *(float2*)(op + n * HID_) = acc;
  }

  // singles: rows 19..23 = embed_tab[ids[95+j]]
#pragma unroll
  for (int j = 0; j < 5; ++j) {
    const int id = s_ids[NG_ * GS_ + j];
    *(float2*)(op + (NG_ + j) * HID_) =
        *(const float2*)&embed_tab[id * HID_ + 2 * t];
  }
}

// ---------------------------------------------------------------------------
extern "C" void kernel_launch(void* const* d_in, const int* in_sizes, int n_in,
                              void* d_out, int out_size, void* d_ws, size_t ws_size,
                              hipStream_t stream) {
  const int*   src_ids = (const int*)  d_in[0];
  const float* dist    = (const float*)d_in[1];
  const float* attn_w  = (const float*)d_in[2];
  const float* valemb  = (const float*)d_in[3];
  const float* ffn_w   = (const float*)d_in[4];
  const float* ffn_b   = (const float*)d_in[5];
  const float* emb_tab = (const float*)d_in[6];
  const float* fire_c  = (const float*)d_in[7];
  const float* fire_w1 = (const float*)d_in[8];
  const float* fire_w2 = (const float*)d_in[9];

  float* out  = (float*)d_out;
  float* ws   = (float*)d_ws;
  float* bias = ws;         // 100 floats
  float* W2   = ws + 128;   // 24*512 floats (16B-aligned)

  hipLaunchKernelGGL(prep_kernel, dim3(97), dim3(128), 0, stream,
                     dist, valemb, ffn_w, fire_c, fire_w1, fire_w2, bias, W2);
  hipLaunchKernelGGL(main_kernel, dim3(B_ * L_), dim3(256), 0, stream,
                     src_ids, attn_w, emb_tab, ffn_b, bias, W2, out);
}